// Round 8
// baseline (441.087 us; speedup 1.0000x reference)
//
#include <hip/hip_runtime.h>

#define Nn 40000
#define Ee 600000
#define Hh 128
#define Gg 32
#define Cc 6
#define NB 157              // ceil(Nn/256) scan blocks
#define CHT (Nn * 16)       // elements per 16-feature chunk table (640000)

typedef __bf16 bf16x8 __attribute__((ext_vector_type(8)));
typedef float floatx4 __attribute__((ext_vector_type(4)));
typedef unsigned short u16;
typedef unsigned int u32;

__device__ __forceinline__ float b2f(u32 u) {
    union { u32 i; float f; } v; v.i = u << 16; return v.f;
}
__device__ __forceinline__ float b2f_hi(u32 u) {
    union { u32 i; float f; } v; v.i = u & 0xffff0000u; return v.f;
}
__device__ __forceinline__ u16 f2b(float f) {
    union { float f; u32 i; } v; v.f = f;
    u32 r = v.i + 0x7fffu + ((v.i >> 16) & 1u);   // RNE
    return (u16)(r >> 16);
}
__device__ __forceinline__ u32 pack2(float a, float b) {
    return (u32)f2b(a) | ((u32)f2b(b) << 16);
}

// ---------------- init ----------------
__global__ __launch_bounds__(256) void k_init(int* counts, float* emb, int* gcnt) {
    int i = blockIdx.x * 256 + threadIdx.x;
    if (i < Nn) counts[i] = 0;
    if (i < Gg * Hh) emb[i] = 0.f;
    if (i < Gg) gcnt[i] = 0;
}

__global__ __launch_bounds__(256) void k_count(const int* __restrict__ dst, int* __restrict__ counts) {
    int i = blockIdx.x * 256 + threadIdx.x;
    if (i < Ee) atomicAdd(&counts[dst[i]], 1);
}

// ---------------- 3-phase multi-block exclusive scan ----------------
__global__ __launch_bounds__(256) void k_scan1(const int* __restrict__ counts, int* __restrict__ bsum) {
    __shared__ int sm[256];
    int t = threadIdx.x;
    int i = blockIdx.x * 256 + t;
    sm[t] = (i < Nn) ? counts[i] : 0;
    __syncthreads();
    for (int ofs = 128; ofs > 0; ofs >>= 1) {
        if (t < ofs) sm[t] += sm[t + ofs];
        __syncthreads();
    }
    if (t == 0) bsum[blockIdx.x] = sm[0];
}

__global__ __launch_bounds__(256) void k_scan2(const int* __restrict__ bsum, int* __restrict__ boff,
                                               int* __restrict__ row_ptr) {
    __shared__ int sm[256];
    int t = threadIdx.x;
    int v = (t < NB) ? bsum[t] : 0;
    sm[t] = v;
    __syncthreads();
    for (int ofs = 1; ofs < 256; ofs <<= 1) {
        int u = (t >= ofs) ? sm[t - ofs] : 0;
        __syncthreads();
        sm[t] += u;
        __syncthreads();
    }
    if (t < NB) boff[t] = sm[t] - v;
    if (t == 255) row_ptr[Nn] = sm[255];
}

// cursor may alias counts — each thread reads counts[i] before writing cursor[i].
__global__ __launch_bounds__(256) void k_scan3(const int* counts, const int* __restrict__ boff,
                                               int* row_ptr, int* cursor, float* dinv) {
    __shared__ int sm[256];
    int t = threadIdx.x;
    int i = blockIdx.x * 256 + t;
    int c = (i < Nn) ? counts[i] : 0;
    sm[t] = c;
    __syncthreads();
    for (int ofs = 1; ofs < 256; ofs <<= 1) {
        int u = (t >= ofs) ? sm[t - ofs] : 0;
        __syncthreads();
        sm[t] += u;
        __syncthreads();
    }
    if (i < Nn) {
        int excl = sm[t] - c + boff[blockIdx.x];
        row_ptr[i] = excl;
        cursor[i] = excl;
        dinv[i] = rsqrtf((float)(c + 1));
    }
}

__global__ __launch_bounds__(256) void k_scatter(const int* __restrict__ src, const int* __restrict__ dst,
                                                 int* __restrict__ cursor, int* __restrict__ colidx) {
    int i = blockIdx.x * 256 + threadIdx.x;
    if (i < Ee) {
        int d = dst[i];
        int p = atomicAdd(&cursor[d], 1);
        if ((u32)p < (u32)Ee) colidx[p] = src[i];
    }
}

// ---------------- f32 -> bf16 cast into chunk-major layout ----------------
// xb[chunk][node][16], chunk = feature/16. Thread handles 8 features (one half-chunk row).
__global__ __launch_bounds__(256) void k_cast(const float* __restrict__ x, u16* __restrict__ xb) {
    int t = blockIdx.x * 256 + threadIdx.x;      // 640000 threads
    int node = t >> 4, seg = t & 15;
    int chunk = seg >> 1, off8 = (seg & 1) * 8;
    const float* src = x + (size_t)node * 128 + seg * 8;
    float4 v0 = *(const float4*)src;
    float4 v1 = *(const float4*)(src + 4);
    uint4 o = { pack2(v0.x, v0.y), pack2(v0.z, v0.w), pack2(v1.x, v1.y), pack2(v1.z, v1.w) };
    *(uint4*)(xb + (size_t)chunk * CHT + (size_t)node * 16 + off8) = o;
}

// ---------------- weight packing: f32 [K=128][N=128] -> bf16 MFMA B-fragment order ----------------
__global__ __launch_bounds__(256) void k_pack(const float* w0, const float* w1, const float* w2,
                                              const float* w3, const float* w4, const float* w5,
                                              const float* w6, u16* dst) {
    int idx = blockIdx.x * 256 + threadIdx.x;
    if (idx >= 7 * 16384) return;
    const float* ws[7] = { w0, w1, w2, w3, w4, w5, w6 };
    int mat = idx >> 14, r = idx & 16383;
    int j = r & 7, n = (r >> 3) & 15, q = (r >> 7) & 3, nt = (r >> 9) & 7, t = r >> 12;
    dst[idx] = f2b(ws[mat][(t * 32 + q * 8 + j) * 128 + nt * 16 + n]);
}

// ---------------- chunked aggregations: blockIdx&7 = chunk (XCD-affinity), 8 lanes/node ----------------
__global__ __launch_bounds__(256) void k_agg_plain(const u16* __restrict__ in, u16* __restrict__ out,
                                                   const int* __restrict__ row_ptr, const int* __restrict__ colidx) {
    int chunk = blockIdx.x & 7, nb = blockIdx.x >> 3;
    int sg = threadIdx.x >> 3, l = threadIdx.x & 7;
    int node = nb * 32 + sg;
    const u16* tbl = in + (size_t)chunk * CHT + l * 2;
    int beg = row_ptr[node], end = row_ptr[node + 1];
    float a0 = 0.f, a1 = 0.f;
    int e = beg;
    for (; e + 4 <= end; e += 4) {
        int s0 = colidx[e], s1 = colidx[e + 1], s2 = colidx[e + 2], s3 = colidx[e + 3];
        u32 u0 = *(const u32*)(tbl + (size_t)s0 * 16);
        u32 u1 = *(const u32*)(tbl + (size_t)s1 * 16);
        u32 u2 = *(const u32*)(tbl + (size_t)s2 * 16);
        u32 u3 = *(const u32*)(tbl + (size_t)s3 * 16);
        a0 += b2f(u0) + b2f(u1) + b2f(u2) + b2f(u3);
        a1 += b2f_hi(u0) + b2f_hi(u1) + b2f_hi(u2) + b2f_hi(u3);
    }
    for (; e < end; ++e) {
        u32 u0 = *(const u32*)(tbl + (size_t)colidx[e] * 16);
        a0 += b2f(u0); a1 += b2f_hi(u0);
    }
    *(u32*)(out + (size_t)chunk * CHT + (size_t)node * 16 + l * 2) = pack2(a0, a1);
}

// GCN: out_i = di*sum_s ds*in_s + di^2*in_i
__global__ __launch_bounds__(256) void k_agg_gcn(const u16* __restrict__ in, u16* __restrict__ out,
                                                 const int* __restrict__ row_ptr, const int* __restrict__ colidx,
                                                 const float* __restrict__ dinv) {
    int chunk = blockIdx.x & 7, nb = blockIdx.x >> 3;
    int sg = threadIdx.x >> 3, l = threadIdx.x & 7;
    int node = nb * 32 + sg;
    const u16* tbl = in + (size_t)chunk * CHT + l * 2;
    int beg = row_ptr[node], end = row_ptr[node + 1];
    float di = dinv[node];
    float a0 = 0.f, a1 = 0.f;
    int e = beg;
    for (; e + 4 <= end; e += 4) {
        int s0 = colidx[e], s1 = colidx[e + 1], s2 = colidx[e + 2], s3 = colidx[e + 3];
        float d0 = dinv[s0], d1 = dinv[s1], d2 = dinv[s2], d3 = dinv[s3];
        u32 u0 = *(const u32*)(tbl + (size_t)s0 * 16);
        u32 u1 = *(const u32*)(tbl + (size_t)s1 * 16);
        u32 u2 = *(const u32*)(tbl + (size_t)s2 * 16);
        u32 u3 = *(const u32*)(tbl + (size_t)s3 * 16);
        a0 += d0 * b2f(u0) + d1 * b2f(u1) + d2 * b2f(u2) + d3 * b2f(u3);
        a1 += d0 * b2f_hi(u0) + d1 * b2f_hi(u1) + d2 * b2f_hi(u2) + d3 * b2f_hi(u3);
    }
    for (; e < end; ++e) {
        int s = colidx[e];
        float ds = dinv[s];
        u32 u0 = *(const u32*)(tbl + (size_t)s * 16);
        a0 += ds * b2f(u0); a1 += ds * b2f_hi(u0);
    }
    u32 us = *(const u32*)(tbl + (size_t)node * 16);
    float d2n = di * di;
    a0 = di * a0 + d2n * b2f(us);
    a1 = di * a1 + d2n * b2f_hi(us);
    *(u32*)(out + (size_t)chunk * CHT + (size_t)node * 16 + l * 2) = pack2(a0, a1);
}

// ---------------- MFMA GEMM on chunk-major activations ----------------
// C = [relu]( A1@B1 [+ A2@B2] + bias ); A/C layout [chunk][node][16]. C may alias A1.
__global__ __launch_bounds__(256) void k_gemm(const u16* A1, const u16* __restrict__ Bp1,
                                              const u16* A2, const u16* __restrict__ Bp2,
                                              const float* __restrict__ bias, u16* C,
                                              int dual, int relu) {
    int wid = threadIdx.x >> 6, lane = threadIdx.x & 63;
    int m0 = (blockIdx.x * 4 + wid) * 16;
    int n = lane & 15, q = lane >> 4;
    floatx4 acc[8];
#pragma unroll
    for (int i = 0; i < 8; i++) acc[i] = (floatx4){0.f, 0.f, 0.f, 0.f};

    // A-frag: k0 = t*32 + q*8 -> chunk = k0/16 = 2t + (q>>1), off = (q&1)*8
    int coff = (q >> 1), aoff = (q & 1) * 8;
    const u16* arow = A1 + (size_t)(m0 + n) * 16 + aoff;
#pragma unroll
    for (int t = 0; t < 4; t++) {
        bf16x8 a = *(const bf16x8*)(arow + (size_t)(2 * t + coff) * CHT);
        const u16* bp = Bp1 + t * 4096 + q * 128 + n * 8;
#pragma unroll
        for (int nt = 0; nt < 8; nt++) {
            bf16x8 b = *(const bf16x8*)(bp + nt * 512);
            acc[nt] = __builtin_amdgcn_mfma_f32_16x16x32_bf16(a, b, acc[nt], 0, 0, 0);
        }
    }
    if (dual) {
        const u16* arow2 = A2 + (size_t)(m0 + n) * 16 + aoff;
#pragma unroll
        for (int t = 0; t < 4; t++) {
            bf16x8 a = *(const bf16x8*)(arow2 + (size_t)(2 * t + coff) * CHT);
            const u16* bp = Bp2 + t * 4096 + q * 128 + n * 8;
#pragma unroll
            for (int nt = 0; nt < 8; nt++) {
                bf16x8 b = *(const bf16x8*)(bp + nt * 512);
                acc[nt] = __builtin_amdgcn_mfma_f32_16x16x32_bf16(a, b, acc[nt], 0, 0, 0);
            }
        }
    }
    // D: row = q*4 + r, col = nt*16 + n -> chunk = nt, off = n
#pragma unroll
    for (int nt = 0; nt < 8; nt++) {
        float bv = bias[nt * 16 + n];
        u16* cb = C + (size_t)nt * CHT + n;
#pragma unroll
        for (int r = 0; r < 4; r++) {
            float v = acc[nt][r] + bv;
            if (relu) v = fmaxf(v, 0.f);
            cb[(size_t)(m0 + q * 4 + r) * 16] = f2b(v);
        }
    }
}

// ---------------- mean-pool (batch is sorted), chunk-major bf16 in ----------------
__global__ __launch_bounds__(128) void k_pool(const u16* __restrict__ h, const int* __restrict__ batch,
                                              float* __restrict__ emb, int* __restrict__ gcnt) {
    int f = threadIdx.x;
    const u16* tbl = h + (size_t)(f >> 4) * CHT + (f & 15);
    int base = blockIdx.x * 64;
    float acc = 0.f; int cnt = 0;
    int curg = batch[base];
    for (int i = 0; i < 64; i++) {
        int node = base + i;
        int g = batch[node];
        if (g != curg) {
            atomicAdd(&emb[curg * 128 + f], acc);
            if (f == 0) atomicAdd(&gcnt[curg], cnt);
            acc = 0.f; cnt = 0; curg = g;
        }
        acc += b2f((u32)tbl[(size_t)node * 16]);
        cnt++;
    }
    atomicAdd(&emb[curg * 128 + f], acc);
    if (f == 0) atomicAdd(&gcnt[curg], cnt);
}

// ---------------- final: embedding + logits (f32 out) ----------------
__global__ __launch_bounds__(256) void k_final(const float* __restrict__ emb, const int* __restrict__ gcnt,
                                               const float* __restrict__ lw, const float* __restrict__ lb,
                                               float* __restrict__ out) {
    int t = threadIdx.x;
    for (int i = t; i < Gg * Hh; i += 256) {
        int g = i >> 7;
        float c = fmaxf((float)gcnt[g], 1.f);
        out[Gg * Cc + i] = emb[i] / c;
    }
    if (t < Gg * Cc) {
        int g = t / Cc, c = t % Cc;
        float cn = fmaxf((float)gcnt[g], 1.f);
        float s = lb[c];
        for (int f = 0; f < Hh; f++)
            s += (emb[g * 128 + f] / cn) * lw[f * Cc + c];
        out[t] = s;
    }
}

extern "C" void kernel_launch(void* const* d_in, const int* in_sizes, int n_in,
                              void* d_out, int out_size, void* d_ws, size_t ws_size,
                              hipStream_t stream) {
    const float* x       = (const float*)d_in[0];
    const int*   ei      = (const int*)d_in[1];
    const int*   batch   = (const int*)d_in[2];
    const float* w1_root = (const float*)d_in[3];
    const float* w1_rel  = (const float*)d_in[4];
    const float* b1      = (const float*)d_in[5];
    const float* w2_root = (const float*)d_in[6];
    const float* w2_rel  = (const float*)d_in[7];
    const float* b2      = (const float*)d_in[8];
    const float* w3      = (const float*)d_in[9];
    const float* b3      = (const float*)d_in[10];
    const float* w4      = (const float*)d_in[11];
    const float* b4      = (const float*)d_in[12];
    const float* w5      = (const float*)d_in[13];
    const float* b5      = (const float*)d_in[14];
    const float* lw      = (const float*)d_in[15];
    const float* lb      = (const float*)d_in[16];
    const int* srcp = ei;
    const int* dstp = ei + Ee;
    float* out = (float*)d_out;

    char* w = (char*)d_ws;
    size_t off = 0;
    auto alloc = [&](size_t bytes) { size_t r = off; off += (bytes + 255) & ~(size_t)255; return r; };
    int*   counts  = (int*)(w + alloc(Nn * 4));          // doubles as scatter cursor
    int*   row_ptr = (int*)(w + alloc((Nn + 1) * 4));
    int*   colidx  = (int*)(w + alloc((size_t)Ee * 4));
    float* dinv    = (float*)(w + alloc(Nn * 4));
    float* emb     = (float*)(w + alloc(Gg * Hh * 4));
    int*   gcnt    = (int*)(w + alloc(Gg * 4));
    int*   bsum    = (int*)(w + alloc(NB * 4));
    int*   boff    = (int*)(w + alloc(256 * 4));
    u16*   pw      = (u16*)(w + alloc(7 * 16384 * 2));
    u16*   xb      = (u16*)(w + alloc((size_t)Nn * Hh * 2));
    u16*   agg     = (u16*)(w + alloc((size_t)Nn * Hh * 2));
    u16*   hA      = (u16*)(w + alloc((size_t)Nn * Hh * 2));
    (void)ws_size;

    u16* pw1r = pw + 0 * 16384;
    u16* pw1l = pw + 1 * 16384;
    u16* pw2r = pw + 2 * 16384;
    u16* pw2l = pw + 3 * 16384;
    u16* pw3  = pw + 4 * 16384;
    u16* pw4  = pw + 5 * 16384;
    u16* pw5  = pw + 6 * 16384;
    const u16* nil = (const u16*)nullptr;

    // CSR build + casts/packs
    hipLaunchKernelGGL(k_init, dim3(157), dim3(256), 0, stream, counts, emb, gcnt);
    hipLaunchKernelGGL(k_count, dim3((Ee + 255) / 256), dim3(256), 0, stream, dstp, counts);
    hipLaunchKernelGGL(k_scan1, dim3(NB), dim3(256), 0, stream, counts, bsum);
    hipLaunchKernelGGL(k_scan2, dim3(1), dim3(256), 0, stream, bsum, boff, row_ptr);
    hipLaunchKernelGGL(k_scan3, dim3(NB), dim3(256), 0, stream, counts, boff, row_ptr, counts, dinv);
    hipLaunchKernelGGL(k_scatter, dim3((Ee + 255) / 256), dim3(256), 0, stream, srcp, dstp, counts, colidx);
    hipLaunchKernelGGL(k_cast, dim3(Nn * 16 / 256), dim3(256), 0, stream, x, xb);
    hipLaunchKernelGGL(k_pack, dim3((7 * 16384 + 255) / 256), dim3(256), 0, stream,
                       w1_root, w1_rel, w2_root, w2_rel, w3, w4, w5, pw);

    // layer 1 (GraphConv): hA = relu(xb@w1_root + agg(xb)@w1_rel + b1)
    hipLaunchKernelGGL(k_agg_plain, dim3(Nn / 32 * 8), dim3(256), 0, stream, xb, agg, row_ptr, colidx);
    hipLaunchKernelGGL(k_gemm, dim3(Nn / 64), dim3(256), 0, stream, xb, pw1r, agg, pw1l, b1, hA, 1, 1);
    // layer 2 (GraphConv), GEMM in-place on hA
    hipLaunchKernelGGL(k_agg_plain, dim3(Nn / 32 * 8), dim3(256), 0, stream, hA, agg, row_ptr, colidx);
    hipLaunchKernelGGL(k_gemm, dim3(Nn / 64), dim3(256), 0, stream, hA, pw2r, agg, pw2l, b2, hA, 1, 1);
    // layers 3..5 (GCNConv)
    hipLaunchKernelGGL(k_agg_gcn, dim3(Nn / 32 * 8), dim3(256), 0, stream, hA, agg, row_ptr, colidx, dinv);
    hipLaunchKernelGGL(k_gemm, dim3(Nn / 64), dim3(256), 0, stream, agg, pw3, nil, nil, b3, hA, 0, 1);
    hipLaunchKernelGGL(k_agg_gcn, dim3(Nn / 32 * 8), dim3(256), 0, stream, hA, agg, row_ptr, colidx, dinv);
    hipLaunchKernelGGL(k_gemm, dim3(Nn / 64), dim3(256), 0, stream, agg, pw4, nil, nil, b4, hA, 0, 1);
    hipLaunchKernelGGL(k_agg_gcn, dim3(Nn / 32 * 8), dim3(256), 0, stream, hA, agg, row_ptr, colidx, dinv);
    hipLaunchKernelGGL(k_gemm, dim3(Nn / 64), dim3(256), 0, stream, agg, pw5, nil, nil, b5, hA, 0, 0);

    // pool + final linear
    hipLaunchKernelGGL(k_pool, dim3(Nn / 64), dim3(128), 0, stream, hA, batch, emb, gcnt);
    hipLaunchKernelGGL(k_final, dim3(1), dim3(256), 0, stream, emb, gcnt, lw, lb, out);
}

// Round 9
// 384.991 us; speedup vs baseline: 1.1457x; 1.1457x over previous
//
#include <hip/hip_runtime.h>

#define Nn 40000
#define Ee 600000
#define Hh 128
#define Gg 32
#define Cc 6
#define NB 157              // ceil(Nn/256) scan blocks
#define CHT (Nn * 32)       // elements per 32-feature chunk table (1,280,000)

typedef __bf16 bf16x8 __attribute__((ext_vector_type(8)));
typedef float floatx4 __attribute__((ext_vector_type(4)));
typedef unsigned short u16;
typedef unsigned int u32;

__device__ __forceinline__ float b2f(u32 u) {
    union { u32 i; float f; } v; v.i = u << 16; return v.f;
}
__device__ __forceinline__ float b2f_hi(u32 u) {
    union { u32 i; float f; } v; v.i = u & 0xffff0000u; return v.f;
}
__device__ __forceinline__ u16 f2b(float f) {
    union { float f; u32 i; } v; v.f = f;
    u32 r = v.i + 0x7fffu + ((v.i >> 16) & 1u);   // RNE
    return (u16)(r >> 16);
}
__device__ __forceinline__ u32 pack2(float a, float b) {
    return (u32)f2b(a) | ((u32)f2b(b) << 16);
}

// ---------------- init ----------------
__global__ __launch_bounds__(256) void k_init(int* counts, float* emb, int* gcnt) {
    int i = blockIdx.x * 256 + threadIdx.x;
    if (i < Nn) counts[i] = 0;
    if (i < Gg * Hh) emb[i] = 0.f;
    if (i < Gg) gcnt[i] = 0;
}

__global__ __launch_bounds__(256) void k_count(const int* __restrict__ dst, int* __restrict__ counts) {
    int i = blockIdx.x * 256 + threadIdx.x;
    if (i < Ee) atomicAdd(&counts[dst[i]], 1);
}

// ---------------- 3-phase multi-block exclusive scan ----------------
__global__ __launch_bounds__(256) void k_scan1(const int* __restrict__ counts, int* __restrict__ bsum) {
    __shared__ int sm[256];
    int t = threadIdx.x;
    int i = blockIdx.x * 256 + t;
    sm[t] = (i < Nn) ? counts[i] : 0;
    __syncthreads();
    for (int ofs = 128; ofs > 0; ofs >>= 1) {
        if (t < ofs) sm[t] += sm[t + ofs];
        __syncthreads();
    }
    if (t == 0) bsum[blockIdx.x] = sm[0];
}

__global__ __launch_bounds__(256) void k_scan2(const int* __restrict__ bsum, int* __restrict__ boff,
                                               int* __restrict__ row_ptr) {
    __shared__ int sm[256];
    int t = threadIdx.x;
    int v = (t < NB) ? bsum[t] : 0;
    sm[t] = v;
    __syncthreads();
    for (int ofs = 1; ofs < 256; ofs <<= 1) {
        int u = (t >= ofs) ? sm[t - ofs] : 0;
        __syncthreads();
        sm[t] += u;
        __syncthreads();
    }
    if (t < NB) boff[t] = sm[t] - v;
    if (t == 255) row_ptr[Nn] = sm[255];
}

// cursor may alias counts — each thread reads counts[i] before writing cursor[i].
__global__ __launch_bounds__(256) void k_scan3(const int* counts, const int* __restrict__ boff,
                                               int* row_ptr, int* cursor, float* dinv) {
    __shared__ int sm[256];
    int t = threadIdx.x;
    int i = blockIdx.x * 256 + t;
    int c = (i < Nn) ? counts[i] : 0;
    sm[t] = c;
    __syncthreads();
    for (int ofs = 1; ofs < 256; ofs <<= 1) {
        int u = (t >= ofs) ? sm[t - ofs] : 0;
        __syncthreads();
        sm[t] += u;
        __syncthreads();
    }
    if (i < Nn) {
        int excl = sm[t] - c + boff[blockIdx.x];
        row_ptr[i] = excl;
        cursor[i] = excl;
        dinv[i] = rsqrtf((float)(c + 1));
    }
}

__global__ __launch_bounds__(256) void k_scatter(const int* __restrict__ src, const int* __restrict__ dst,
                                                 int* __restrict__ cursor, int* __restrict__ colidx) {
    int i = blockIdx.x * 256 + threadIdx.x;
    if (i < Ee) {
        int d = dst[i];
        int p = atomicAdd(&cursor[d], 1);
        if ((u32)p < (u32)Ee) colidx[p] = src[i];
    }
}

// ---------------- f32 -> bf16 cast into 32-feature chunk-major layout ----------------
// xb[chunk][node][32], chunk = feature/32.
__global__ __launch_bounds__(256) void k_cast(const float* __restrict__ x, u16* __restrict__ xb) {
    int t = blockIdx.x * 256 + threadIdx.x;      // 640000 threads, 8 features each
    int node = t >> 4, seg = t & 15;
    int chunk = seg >> 2, part = seg & 3;
    const float* src = x + (size_t)node * 128 + chunk * 32 + part * 8;
    float4 v0 = *(const float4*)src;
    float4 v1 = *(const float4*)(src + 4);
    uint4 o = { pack2(v0.x, v0.y), pack2(v0.z, v0.w), pack2(v1.x, v1.y), pack2(v1.z, v1.w) };
    *(uint4*)(xb + (size_t)chunk * CHT + (size_t)node * 32 + part * 8) = o;
}

// ---------------- weight packing: f32 [K=128][N=128] -> bf16 MFMA B-fragment order ----------------
__global__ __launch_bounds__(256) void k_pack(const float* w0, const float* w1, const float* w2,
                                              const float* w3, const float* w4, const float* w5,
                                              const float* w6, u16* dst) {
    int idx = blockIdx.x * 256 + threadIdx.x;
    if (idx >= 7 * 16384) return;
    const float* ws[7] = { w0, w1, w2, w3, w4, w5, w6 };
    int mat = idx >> 14, r = idx & 16383;
    int j = r & 7, n = (r >> 3) & 15, q = (r >> 7) & 3, nt = (r >> 9) & 7, t = r >> 12;
    dst[idx] = f2b(ws[mat][(t * 32 + q * 8 + j) * 128 + nt * 16 + n]);
}

// ---------------- chunked aggregations ----------------
// blockIdx&3 = chunk (per-chunk table 2.56 MB -> XCD-L2 resident).
// Wave: 4 nodes x 4 edges x 4 slices; each lane loads dwordx4 (16 B); main loop 8 edges deep.
// Cross-lane butterfly over edge_sub folds the 4 edge partials.
#define ACC8_FMA(V, d)                                   \
    a0 += (d) * b2f((V).x);  a1 += (d) * b2f_hi((V).x);  \
    a2 += (d) * b2f((V).y);  a3 += (d) * b2f_hi((V).y);  \
    a4 += (d) * b2f((V).z);  a5 += (d) * b2f_hi((V).z);  \
    a6 += (d) * b2f((V).w);  a7 += (d) * b2f_hi((V).w);

__global__ __launch_bounds__(256) void k_agg_plain(const u16* __restrict__ in, u16* __restrict__ out,
                                                   const int* __restrict__ row_ptr, const int* __restrict__ colidx) {
    int chunk = blockIdx.x & 3, nb = blockIdx.x >> 2;
    int wave = threadIdx.x >> 6, lane = threadIdx.x & 63;
    int node_sub = lane >> 4, edge_sub = (lane >> 2) & 3, slice = lane & 3;
    int node = nb * 16 + wave * 4 + node_sub;
    const u16* tbl = in + (size_t)chunk * CHT + slice * 8;
    int beg = row_ptr[node], end = row_ptr[node + 1];
    float a0 = 0.f, a1 = 0.f, a2 = 0.f, a3 = 0.f, a4 = 0.f, a5 = 0.f, a6 = 0.f, a7 = 0.f;
    int e = beg;
    for (; e + 8 <= end; e += 8) {
        int s0 = colidx[e + edge_sub];
        int s1 = colidx[e + 4 + edge_sub];
        uint4 v0 = *(const uint4*)(tbl + (size_t)s0 * 32);
        uint4 v1 = *(const uint4*)(tbl + (size_t)s1 * 32);
        ACC8_FMA(v0, 1.f) ACC8_FMA(v1, 1.f)
    }
    for (; e < end; e += 4) {
        int ee = e + edge_sub;
        if (ee < end) {
            uint4 v0 = *(const uint4*)(tbl + (size_t)colidx[ee] * 32);
            ACC8_FMA(v0, 1.f)
        }
    }
    // fold edge partials (xor lanes 4 and 8)
    a0 += __shfl_xor(a0, 4); a1 += __shfl_xor(a1, 4); a2 += __shfl_xor(a2, 4); a3 += __shfl_xor(a3, 4);
    a4 += __shfl_xor(a4, 4); a5 += __shfl_xor(a5, 4); a6 += __shfl_xor(a6, 4); a7 += __shfl_xor(a7, 4);
    a0 += __shfl_xor(a0, 8); a1 += __shfl_xor(a1, 8); a2 += __shfl_xor(a2, 8); a3 += __shfl_xor(a3, 8);
    a4 += __shfl_xor(a4, 8); a5 += __shfl_xor(a5, 8); a6 += __shfl_xor(a6, 8); a7 += __shfl_xor(a7, 8);
    if (edge_sub == 0) {
        uint4 o = { pack2(a0, a1), pack2(a2, a3), pack2(a4, a5), pack2(a6, a7) };
        *(uint4*)(out + (size_t)chunk * CHT + (size_t)node * 32 + slice * 8) = o;
    }
}

// GCN: out_i = di*sum_s ds*in_s + di^2*in_i
__global__ __launch_bounds__(256) void k_agg_gcn(const u16* __restrict__ in, u16* __restrict__ out,
                                                 const int* __restrict__ row_ptr, const int* __restrict__ colidx,
                                                 const float* __restrict__ dinv) {
    int chunk = blockIdx.x & 3, nb = blockIdx.x >> 2;
    int wave = threadIdx.x >> 6, lane = threadIdx.x & 63;
    int node_sub = lane >> 4, edge_sub = (lane >> 2) & 3, slice = lane & 3;
    int node = nb * 16 + wave * 4 + node_sub;
    const u16* tbl = in + (size_t)chunk * CHT + slice * 8;
    int beg = row_ptr[node], end = row_ptr[node + 1];
    float a0 = 0.f, a1 = 0.f, a2 = 0.f, a3 = 0.f, a4 = 0.f, a5 = 0.f, a6 = 0.f, a7 = 0.f;
    int e = beg;
    for (; e + 8 <= end; e += 8) {
        int s0 = colidx[e + edge_sub];
        int s1 = colidx[e + 4 + edge_sub];
        float d0 = dinv[s0], d1 = dinv[s1];
        uint4 v0 = *(const uint4*)(tbl + (size_t)s0 * 32);
        uint4 v1 = *(const uint4*)(tbl + (size_t)s1 * 32);
        ACC8_FMA(v0, d0) ACC8_FMA(v1, d1)
    }
    for (; e < end; e += 4) {
        int ee = e + edge_sub;
        if (ee < end) {
            int s = colidx[ee];
            float ds = dinv[s];
            uint4 v0 = *(const uint4*)(tbl + (size_t)s * 32);
            ACC8_FMA(v0, ds)
        }
    }
    a0 += __shfl_xor(a0, 4); a1 += __shfl_xor(a1, 4); a2 += __shfl_xor(a2, 4); a3 += __shfl_xor(a3, 4);
    a4 += __shfl_xor(a4, 4); a5 += __shfl_xor(a5, 4); a6 += __shfl_xor(a6, 4); a7 += __shfl_xor(a7, 4);
    a0 += __shfl_xor(a0, 8); a1 += __shfl_xor(a1, 8); a2 += __shfl_xor(a2, 8); a3 += __shfl_xor(a3, 8);
    a4 += __shfl_xor(a4, 8); a5 += __shfl_xor(a5, 8); a6 += __shfl_xor(a6, 8); a7 += __shfl_xor(a7, 8);
    if (edge_sub == 0) {
        float di = dinv[node];
        float d2n = di * di;
        uint4 us = *(const uint4*)(tbl + (size_t)node * 32);
        a0 = di * a0 + d2n * b2f(us.x);  a1 = di * a1 + d2n * b2f_hi(us.x);
        a2 = di * a2 + d2n * b2f(us.y);  a3 = di * a3 + d2n * b2f_hi(us.y);
        a4 = di * a4 + d2n * b2f(us.z);  a5 = di * a5 + d2n * b2f_hi(us.z);
        a6 = di * a6 + d2n * b2f(us.w);  a7 = di * a7 + d2n * b2f_hi(us.w);
        uint4 o = { pack2(a0, a1), pack2(a2, a3), pack2(a4, a5), pack2(a6, a7) };
        *(uint4*)(out + (size_t)chunk * CHT + (size_t)node * 32 + slice * 8) = o;
    }
}

// ---------------- MFMA GEMM on 32-feature chunk-major activations ----------------
// C = [relu]( A1@B1 [+ A2@B2] + bias ); A/C layout [chunk][node][32]. C may alias A1.
__global__ __launch_bounds__(256) void k_gemm(const u16* A1, const u16* __restrict__ Bp1,
                                              const u16* A2, const u16* __restrict__ Bp2,
                                              const float* __restrict__ bias, u16* C,
                                              int dual, int relu) {
    int wid = threadIdx.x >> 6, lane = threadIdx.x & 63;
    int m0 = (blockIdx.x * 4 + wid) * 16;
    int n = lane & 15, q = lane >> 4;
    floatx4 acc[8];
#pragma unroll
    for (int i = 0; i < 8; i++) acc[i] = (floatx4){0.f, 0.f, 0.f, 0.f};

    // A-frag: k-tile t covers features 32t..32t+31 = chunk t; within-chunk offset q*8
    const u16* arow = A1 + (size_t)(m0 + n) * 32 + q * 8;
#pragma unroll
    for (int t = 0; t < 4; t++) {
        bf16x8 a = *(const bf16x8*)(arow + (size_t)t * CHT);
        const u16* bp = Bp1 + t * 4096 + q * 128 + n * 8;
#pragma unroll
        for (int nt = 0; nt < 8; nt++) {
            bf16x8 b = *(const bf16x8*)(bp + nt * 512);
            acc[nt] = __builtin_amdgcn_mfma_f32_16x16x32_bf16(a, b, acc[nt], 0, 0, 0);
        }
    }
    if (dual) {
        const u16* arow2 = A2 + (size_t)(m0 + n) * 32 + q * 8;
#pragma unroll
        for (int t = 0; t < 4; t++) {
            bf16x8 a = *(const bf16x8*)(arow2 + (size_t)t * CHT);
            const u16* bp = Bp2 + t * 4096 + q * 128 + n * 8;
#pragma unroll
            for (int nt = 0; nt < 8; nt++) {
                bf16x8 b = *(const bf16x8*)(bp + nt * 512);
                acc[nt] = __builtin_amdgcn_mfma_f32_16x16x32_bf16(a, b, acc[nt], 0, 0, 0);
            }
        }
    }
    // D: row = q*4 + r, col = nt*16 + n -> chunk = nt>>1, off = (nt&1)*16 + n
#pragma unroll
    for (int nt = 0; nt < 8; nt++) {
        float bv = bias[nt * 16 + n];
        u16* cb = C + (size_t)(nt >> 1) * CHT + (nt & 1) * 16 + n;
#pragma unroll
        for (int r = 0; r < 4; r++) {
            float v = acc[nt][r] + bv;
            if (relu) v = fmaxf(v, 0.f);
            cb[(size_t)(m0 + q * 4 + r) * 32] = f2b(v);
        }
    }
}

// ---------------- mean-pool (batch is sorted), chunk-major bf16 in ----------------
__global__ __launch_bounds__(128) void k_pool(const u16* __restrict__ h, const int* __restrict__ batch,
                                              float* __restrict__ emb, int* __restrict__ gcnt) {
    int f = threadIdx.x;
    const u16* tbl = h + (size_t)(f >> 5) * CHT + (f & 31);
    int base = blockIdx.x * 64;
    float acc = 0.f; int cnt = 0;
    int curg = batch[base];
    for (int i = 0; i < 64; i++) {
        int node = base + i;
        int g = batch[node];
        if (g != curg) {
            atomicAdd(&emb[curg * 128 + f], acc);
            if (f == 0) atomicAdd(&gcnt[curg], cnt);
            acc = 0.f; cnt = 0; curg = g;
        }
        acc += b2f((u32)tbl[(size_t)node * 32]);
        cnt++;
    }
    atomicAdd(&emb[curg * 128 + f], acc);
    if (f == 0) atomicAdd(&gcnt[curg], cnt);
}

// ---------------- final: embedding + logits (f32 out) ----------------
__global__ __launch_bounds__(256) void k_final(const float* __restrict__ emb, const int* __restrict__ gcnt,
                                               const float* __restrict__ lw, const float* __restrict__ lb,
                                               float* __restrict__ out) {
    int t = threadIdx.x;
    for (int i = t; i < Gg * Hh; i += 256) {
        int g = i >> 7;
        float c = fmaxf((float)gcnt[g], 1.f);
        out[Gg * Cc + i] = emb[i] / c;
    }
    if (t < Gg * Cc) {
        int g = t / Cc, c = t % Cc;
        float cn = fmaxf((float)gcnt[g], 1.f);
        float s = lb[c];
        for (int f = 0; f < Hh; f++)
            s += (emb[g * 128 + f] / cn) * lw[f * Cc + c];
        out[t] = s;
    }
}

extern "C" void kernel_launch(void* const* d_in, const int* in_sizes, int n_in,
                              void* d_out, int out_size, void* d_ws, size_t ws_size,
                              hipStream_t stream) {
    const float* x       = (const float*)d_in[0];
    const int*   ei      = (const int*)d_in[1];
    const int*   batch   = (const int*)d_in[2];
    const float* w1_root = (const float*)d_in[3];
    const float* w1_rel  = (const float*)d_in[4];
    const float* b1      = (const float*)d_in[5];
    const float* w2_root = (const float*)d_in[6];
    const float* w2_rel  = (const float*)d_in[7];
    const float* b2      = (const float*)d_in[8];
    const float* w3      = (const float*)d_in[9];
    const float* b3      = (const float*)d_in[10];
    const float* w4      = (const float*)d_in[11];
    const float* b4      = (const float*)d_in[12];
    const float* w5      = (const float*)d_in[13];
    const float* b5      = (const float*)d_in[14];
    const float* lw      = (const float*)d_in[15];
    const float* lb      = (const float*)d_in[16];
    const int* srcp = ei;
    const int* dstp = ei + Ee;
    float* out = (float*)d_out;

    char* w = (char*)d_ws;
    size_t off = 0;
    auto alloc = [&](size_t bytes) { size_t r = off; off += (bytes + 255) & ~(size_t)255; return r; };
    int*   counts  = (int*)(w + alloc(Nn * 4));          // doubles as scatter cursor
    int*   row_ptr = (int*)(w + alloc((Nn + 1) * 4));
    int*   colidx  = (int*)(w + alloc((size_t)Ee * 4));
    float* dinv    = (float*)(w + alloc(Nn * 4));
    float* emb     = (float*)(w + alloc(Gg * Hh * 4));
    int*   gcnt    = (int*)(w + alloc(Gg * 4));
    int*   bsum    = (int*)(w + alloc(NB * 4));
    int*   boff    = (int*)(w + alloc(256 * 4));
    u16*   pw      = (u16*)(w + alloc(7 * 16384 * 2));
    u16*   xb      = (u16*)(w + alloc((size_t)Nn * Hh * 2));
    u16*   agg     = (u16*)(w + alloc((size_t)Nn * Hh * 2));
    u16*   hA      = (u16*)(w + alloc((size_t)Nn * Hh * 2));
    (void)ws_size;

    u16* pw1r = pw + 0 * 16384;
    u16* pw1l = pw + 1 * 16384;
    u16* pw2r = pw + 2 * 16384;
    u16* pw2l = pw + 3 * 16384;
    u16* pw3  = pw + 4 * 16384;
    u16* pw4  = pw + 5 * 16384;
    u16* pw5  = pw + 6 * 16384;
    const u16* nil = (const u16*)nullptr;

    // CSR build + casts/packs
    hipLaunchKernelGGL(k_init, dim3(157), dim3(256), 0, stream, counts, emb, gcnt);
    hipLaunchKernelGGL(k_count, dim3((Ee + 255) / 256), dim3(256), 0, stream, dstp, counts);
    hipLaunchKernelGGL(k_scan1, dim3(NB), dim3(256), 0, stream, counts, bsum);
    hipLaunchKernelGGL(k_scan2, dim3(1), dim3(256), 0, stream, bsum, boff, row_ptr);
    hipLaunchKernelGGL(k_scan3, dim3(NB), dim3(256), 0, stream, counts, boff, row_ptr, counts, dinv);
    hipLaunchKernelGGL(k_scatter, dim3((Ee + 255) / 256), dim3(256), 0, stream, srcp, dstp, counts, colidx);
    hipLaunchKernelGGL(k_cast, dim3(Nn * 16 / 256), dim3(256), 0, stream, x, xb);
    hipLaunchKernelGGL(k_pack, dim3((7 * 16384 + 255) / 256), dim3(256), 0, stream,
                       w1_root, w1_rel, w2_root, w2_rel, w3, w4, w5, pw);

    // layer 1 (GraphConv): hA = relu(xb@w1_root + agg(xb)@w1_rel + b1)
    hipLaunchKernelGGL(k_agg_plain, dim3(Nn / 16 * 4), dim3(256), 0, stream, xb, agg, row_ptr, colidx);
    hipLaunchKernelGGL(k_gemm, dim3(Nn / 64), dim3(256), 0, stream, xb, pw1r, agg, pw1l, b1, hA, 1, 1);
    // layer 2 (GraphConv), GEMM in-place on hA
    hipLaunchKernelGGL(k_agg_plain, dim3(Nn / 16 * 4), dim3(256), 0, stream, hA, agg, row_ptr, colidx);
    hipLaunchKernelGGL(k_gemm, dim3(Nn / 64), dim3(256), 0, stream, hA, pw2r, agg, pw2l, b2, hA, 1, 1);
    // layers 3..5 (GCNConv)
    hipLaunchKernelGGL(k_agg_gcn, dim3(Nn / 16 * 4), dim3(256), 0, stream, hA, agg, row_ptr, colidx, dinv);
    hipLaunchKernelGGL(k_gemm, dim3(Nn / 64), dim3(256), 0, stream, agg, pw3, nil, nil, b3, hA, 0, 1);
    hipLaunchKernelGGL(k_agg_gcn, dim3(Nn / 16 * 4), dim3(256), 0, stream, hA, agg, row_ptr, colidx, dinv);
    hipLaunchKernelGGL(k_gemm, dim3(Nn / 64), dim3(256), 0, stream, agg, pw4, nil, nil, b4, hA, 0, 1);
    hipLaunchKernelGGL(k_agg_gcn, dim3(Nn / 16 * 4), dim3(256), 0, stream, hA, agg, row_ptr, colidx, dinv);
    hipLaunchKernelGGL(k_gemm, dim3(Nn / 64), dim3(256), 0, stream, agg, pw5, nil, nil, b5, hA, 0, 0);

    // pool + final linear
    hipLaunchKernelGGL(k_pool, dim3(Nn / 64), dim3(128), 0, stream, hA, batch, emb, gcnt);
    hipLaunchKernelGGL(k_final, dim3(1), dim3(256), 0, stream, emb, gcnt, lw, lb, out);
}

// Round 10
// 383.277 us; speedup vs baseline: 1.1508x; 1.0045x over previous
//
#include <hip/hip_runtime.h>

#define Nn 40000
#define Ee 600000
#define Hh 128
#define Gg 32
#define Cc 6
#define NB 157              // ceil(Nn/256) scan blocks
#define PCAP (Ee + 8 * Nn)  // padded colidx capacity (920000)

typedef __bf16 bf16x8 __attribute__((ext_vector_type(8)));
typedef float floatx4 __attribute__((ext_vector_type(4)));
typedef unsigned short u16;
typedef unsigned int u32;

__device__ __forceinline__ float b2f(u32 u) {
    union { u32 i; float f; } v; v.i = u << 16; return v.f;
}
__device__ __forceinline__ float b2f_hi(u32 u) {
    union { u32 i; float f; } v; v.i = u & 0xffff0000u; return v.f;
}
__device__ __forceinline__ u16 f2b(float f) {
    union { float f; u32 i; } v; v.f = f;
    u32 r = v.i + 0x7fffu + ((v.i >> 16) & 1u);   // RNE
    return (u16)(r >> 16);
}
__device__ __forceinline__ u32 pack2(float a, float b) {
    return (u32)f2b(a) | ((u32)f2b(b) << 16);
}

// ---------------- init ----------------
__global__ __launch_bounds__(256) void k_init(int* counts, float* emb, int* gcnt) {
    int i = blockIdx.x * 256 + threadIdx.x;
    if (i < Nn) counts[i] = 0;
    if (i < Gg * Hh) emb[i] = 0.f;
    if (i < Gg) gcnt[i] = 0;
}

__global__ __launch_bounds__(256) void k_count(const int* __restrict__ dst, int* __restrict__ counts) {
    int i = blockIdx.x * 256 + threadIdx.x;
    if (i < Ee) atomicAdd(&counts[dst[i]], 1);
}

// ---------------- 3-phase multi-block exclusive scan over PADDED counts ----------------
__global__ __launch_bounds__(256) void k_scan1(const int* __restrict__ counts, int* __restrict__ bsum) {
    __shared__ int sm[256];
    int t = threadIdx.x;
    int i = blockIdx.x * 256 + t;
    sm[t] = (i < Nn) ? ((counts[i] + 7) & ~7) : 0;
    __syncthreads();
    for (int ofs = 128; ofs > 0; ofs >>= 1) {
        if (t < ofs) sm[t] += sm[t + ofs];
        __syncthreads();
    }
    if (t == 0) bsum[blockIdx.x] = sm[0];
}

__global__ __launch_bounds__(256) void k_scan2(const int* __restrict__ bsum, int* __restrict__ boff,
                                               int* __restrict__ row_ptr) {
    __shared__ int sm[256];
    int t = threadIdx.x;
    int v = (t < NB) ? bsum[t] : 0;
    sm[t] = v;
    __syncthreads();
    for (int ofs = 1; ofs < 256; ofs <<= 1) {
        int u = (t >= ofs) ? sm[t - ofs] : 0;
        __syncthreads();
        sm[t] += u;
        __syncthreads();
    }
    if (t < NB) boff[t] = sm[t] - v;
    if (t == 255) row_ptr[Nn] = sm[255];       // total padded edges
}

// cursor may alias counts — each thread reads counts[i] before writing cursor[i].
__global__ __launch_bounds__(256) void k_scan3(const int* counts, const int* __restrict__ boff,
                                               int* row_ptr, int* cursor, float* dinv) {
    __shared__ int sm[256];
    int t = threadIdx.x;
    int i = blockIdx.x * 256 + t;
    int c = (i < Nn) ? counts[i] : 0;
    int pc = (c + 7) & ~7;
    sm[t] = pc;
    __syncthreads();
    for (int ofs = 1; ofs < 256; ofs <<= 1) {
        int u = (t >= ofs) ? sm[t - ofs] : 0;
        __syncthreads();
        sm[t] += u;
        __syncthreads();
    }
    if (i < Nn) {
        int excl = sm[t] - pc + boff[blockIdx.x];
        row_ptr[i] = excl;
        cursor[i] = excl;
        dinv[i] = rsqrtf((float)(c + 1));
    }
}

// ---------------- prefill padded colidx with dummy node Nn; zero dummy rows; dinv[Nn]=0 ----------------
__global__ __launch_bounds__(256) void k_prefill(int* __restrict__ pcol, u16* __restrict__ xb,
                                                 u16* __restrict__ hA, float* __restrict__ dinv) {
    int i = blockIdx.x * 256 + threadIdx.x;
    if (i < PCAP / 4) {
        int4 v = { Nn, Nn, Nn, Nn };
        *(int4*)(pcol + i * 4) = v;
    }
    if (blockIdx.x == 0) {
        int t = threadIdx.x;
        uint4 z = { 0, 0, 0, 0 };
        if (t < 16)              *(uint4*)(xb + (size_t)Nn * 128 + t * 8) = z;
        else if (t < 32)         *(uint4*)(hA + (size_t)Nn * 128 + (t - 16) * 8) = z;
        else if (t == 32)        dinv[Nn] = 0.f;
    }
}

__global__ __launch_bounds__(256) void k_scatter(const int* __restrict__ src, const int* __restrict__ dst,
                                                 int* __restrict__ cursor, int* __restrict__ colidx) {
    int i = blockIdx.x * 256 + threadIdx.x;
    if (i < Ee) {
        int d = dst[i];
        int p = atomicAdd(&cursor[d], 1);
        if ((u32)p < (u32)PCAP) colidx[p] = src[i];
    }
}

// ---------------- f32 -> bf16 cast of input features (flat rows) ----------------
__global__ __launch_bounds__(256) void k_cast(const float* __restrict__ x, u16* __restrict__ xb) {
    int i = (blockIdx.x * 256 + threadIdx.x) * 4;
    float4 v = *(const float4*)(x + i);
    ushort4 o = { f2b(v.x), f2b(v.y), f2b(v.z), f2b(v.w) };
    *(ushort4*)(xb + i) = o;
}

// ---------------- weight packing: f32 [K=128][N=128] -> bf16 MFMA B-fragment order ----------------
__global__ __launch_bounds__(256) void k_pack(const float* w0, const float* w1, const float* w2,
                                              const float* w3, const float* w4, const float* w5,
                                              const float* w6, u16* dst) {
    int idx = blockIdx.x * 256 + threadIdx.x;
    if (idx >= 7 * 16384) return;
    const float* ws[7] = { w0, w1, w2, w3, w4, w5, w6 };
    int mat = idx >> 14, r = idx & 16383;
    int j = r & 7, n = (r >> 3) & 15, q = (r >> 7) & 3, nt = (r >> 9) & 7, t = r >> 12;
    dst[idx] = f2b(ws[mat][(t * 32 + q * 8 + j) * 128 + nt * 16 + n]);
}

// ---------------- aggregations: 4 nodes/wave, 16 lanes/node, 8-deep pipelined gathers ----------------
// Padded CSR: every node's range is a multiple of 8; pad edges point at zero row Nn.
#define UNPACK_ADD(V)                                   \
    a0 += b2f((V).x);  a1 += b2f_hi((V).x);             \
    a2 += b2f((V).y);  a3 += b2f_hi((V).y);             \
    a4 += b2f((V).z);  a5 += b2f_hi((V).z);             \
    a6 += b2f((V).w);  a7 += b2f_hi((V).w);

#define UNPACK_FMA(V, d)                                      \
    a0 += (d) * b2f((V).x);  a1 += (d) * b2f_hi((V).x);       \
    a2 += (d) * b2f((V).y);  a3 += (d) * b2f_hi((V).y);       \
    a4 += (d) * b2f((V).z);  a5 += (d) * b2f_hi((V).z);       \
    a6 += (d) * b2f((V).w);  a7 += (d) * b2f_hi((V).w);

__global__ __launch_bounds__(256) void k_agg_plain(const u16* __restrict__ in, u16* __restrict__ out,
                                                   const int* __restrict__ prow, const int* __restrict__ pcol) {
    int wave = threadIdx.x >> 6, lane = threadIdx.x & 63;
    int g = lane >> 4, l = lane & 15;
    int node = (blockIdx.x * 4 + wave) * 4 + g;
    int beg = prow[node], end = prow[node + 1];
    float a0 = 0.f, a1 = 0.f, a2 = 0.f, a3 = 0.f, a4 = 0.f, a5 = 0.f, a6 = 0.f, a7 = 0.f;
    const u16* base = in + l * 8;
    int4 i0 = {0,0,0,0}, i1 = {0,0,0,0};
    if (beg < end) {
        i0 = *(const int4*)(pcol + beg);
        i1 = *(const int4*)(pcol + beg + 4);
    }
    for (int e = beg; e < end; e += 8) {
        int en = (e + 8 < end) ? (e + 8) : beg;      // prefetch next (or harmless reload)
        int4 j0 = *(const int4*)(pcol + en);
        int4 j1 = *(const int4*)(pcol + en + 4);
        uint4 v0 = *(const uint4*)(base + (size_t)i0.x * 128);
        uint4 v1 = *(const uint4*)(base + (size_t)i0.y * 128);
        uint4 v2 = *(const uint4*)(base + (size_t)i0.z * 128);
        uint4 v3 = *(const uint4*)(base + (size_t)i0.w * 128);
        uint4 v4 = *(const uint4*)(base + (size_t)i1.x * 128);
        uint4 v5 = *(const uint4*)(base + (size_t)i1.y * 128);
        uint4 v6 = *(const uint4*)(base + (size_t)i1.z * 128);
        uint4 v7 = *(const uint4*)(base + (size_t)i1.w * 128);
        UNPACK_ADD(v0) UNPACK_ADD(v1) UNPACK_ADD(v2) UNPACK_ADD(v3)
        UNPACK_ADD(v4) UNPACK_ADD(v5) UNPACK_ADD(v6) UNPACK_ADD(v7)
        i0 = j0; i1 = j1;
    }
    uint4 o = { pack2(a0, a1), pack2(a2, a3), pack2(a4, a5), pack2(a6, a7) };
    *(uint4*)(out + (size_t)node * 128 + l * 8) = o;
}

// GCN: out_i = di*sum_s ds*in_s + di^2*in_i   (pad edges: zero row, dinv[Nn]=0)
__global__ __launch_bounds__(256) void k_agg_gcn(const u16* __restrict__ in, u16* __restrict__ out,
                                                 const int* __restrict__ prow, const int* __restrict__ pcol,
                                                 const float* __restrict__ dinv) {
    int wave = threadIdx.x >> 6, lane = threadIdx.x & 63;
    int g = lane >> 4, l = lane & 15;
    int node = (blockIdx.x * 4 + wave) * 4 + g;
    int beg = prow[node], end = prow[node + 1];
    float a0 = 0.f, a1 = 0.f, a2 = 0.f, a3 = 0.f, a4 = 0.f, a5 = 0.f, a6 = 0.f, a7 = 0.f;
    const u16* base = in + l * 8;
    int4 i0 = {0,0,0,0}, i1 = {0,0,0,0};
    if (beg < end) {
        i0 = *(const int4*)(pcol + beg);
        i1 = *(const int4*)(pcol + beg + 4);
    }
    for (int e = beg; e < end; e += 8) {
        int en = (e + 8 < end) ? (e + 8) : beg;
        int4 j0 = *(const int4*)(pcol + en);
        int4 j1 = *(const int4*)(pcol + en + 4);
        float d0 = dinv[i0.x], d1 = dinv[i0.y], d2 = dinv[i0.z], d3 = dinv[i0.w];
        float d4 = dinv[i1.x], d5 = dinv[i1.y], d6 = dinv[i1.z], d7 = dinv[i1.w];
        uint4 v0 = *(const uint4*)(base + (size_t)i0.x * 128);
        uint4 v1 = *(const uint4*)(base + (size_t)i0.y * 128);
        uint4 v2 = *(const uint4*)(base + (size_t)i0.z * 128);
        uint4 v3 = *(const uint4*)(base + (size_t)i0.w * 128);
        uint4 v4 = *(const uint4*)(base + (size_t)i1.x * 128);
        uint4 v5 = *(const uint4*)(base + (size_t)i1.y * 128);
        uint4 v6 = *(const uint4*)(base + (size_t)i1.z * 128);
        uint4 v7 = *(const uint4*)(base + (size_t)i1.w * 128);
        UNPACK_FMA(v0, d0) UNPACK_FMA(v1, d1) UNPACK_FMA(v2, d2) UNPACK_FMA(v3, d3)
        UNPACK_FMA(v4, d4) UNPACK_FMA(v5, d5) UNPACK_FMA(v6, d6) UNPACK_FMA(v7, d7)
        i0 = j0; i1 = j1;
    }
    float di = dinv[node];
    float d2n = di * di;
    uint4 us = *(const uint4*)(base + (size_t)node * 128);
    a0 = di * a0 + d2n * b2f(us.x);  a1 = di * a1 + d2n * b2f_hi(us.x);
    a2 = di * a2 + d2n * b2f(us.y);  a3 = di * a3 + d2n * b2f_hi(us.y);
    a4 = di * a4 + d2n * b2f(us.z);  a5 = di * a5 + d2n * b2f_hi(us.z);
    a6 = di * a6 + d2n * b2f(us.w);  a7 = di * a7 + d2n * b2f_hi(us.w);
    uint4 o = { pack2(a0, a1), pack2(a2, a3), pack2(a4, a5), pack2(a6, a7) };
    *(uint4*)(out + (size_t)node * 128 + l * 8) = o;
}

// ---------------- MFMA GEMM: C = [relu]( A1@B1 [+ A2@B2] + bias ), M=40000, K=N=128, bf16 flat rows ----------------
__global__ __launch_bounds__(256) void k_gemm(const u16* A1, const u16* __restrict__ Bp1,
                                              const u16* A2, const u16* __restrict__ Bp2,
                                              const float* __restrict__ bias, u16* C,
                                              int dual, int relu) {
    int wid = threadIdx.x >> 6, lane = threadIdx.x & 63;
    int m0 = (blockIdx.x * 4 + wid) * 16;
    int n = lane & 15, q = lane >> 4;
    floatx4 acc[8];
#pragma unroll
    for (int i = 0; i < 8; i++) acc[i] = (floatx4){0.f, 0.f, 0.f, 0.f};

    const u16* arow = A1 + (size_t)(m0 + n) * 128 + q * 8;
#pragma unroll
    for (int t = 0; t < 4; t++) {
        bf16x8 a = *(const bf16x8*)(arow + t * 32);
        const u16* bp = Bp1 + t * 4096 + q * 128 + n * 8;
#pragma unroll
        for (int nt = 0; nt < 8; nt++) {
            bf16x8 b = *(const bf16x8*)(bp + nt * 512);
            acc[nt] = __builtin_amdgcn_mfma_f32_16x16x32_bf16(a, b, acc[nt], 0, 0, 0);
        }
    }
    if (dual) {
        const u16* arow2 = A2 + (size_t)(m0 + n) * 128 + q * 8;
#pragma unroll
        for (int t = 0; t < 4; t++) {
            bf16x8 a = *(const bf16x8*)(arow2 + t * 32);
            const u16* bp = Bp2 + t * 4096 + q * 128 + n * 8;
#pragma unroll
            for (int nt = 0; nt < 8; nt++) {
                bf16x8 b = *(const bf16x8*)(bp + nt * 512);
                acc[nt] = __builtin_amdgcn_mfma_f32_16x16x32_bf16(a, b, acc[nt], 0, 0, 0);
            }
        }
    }
#pragma unroll
    for (int nt = 0; nt < 8; nt++) {
        int col = nt * 16 + n;
        float bv = bias[col];
#pragma unroll
        for (int r = 0; r < 4; r++) {
            float v = acc[nt][r] + bv;
            if (relu) v = fmaxf(v, 0.f);
            C[(size_t)(m0 + q * 4 + r) * 128 + col] = f2b(v);
        }
    }
}

// ---------------- mean-pool (batch is sorted), bf16 in, f32 accum ----------------
__global__ __launch_bounds__(128) void k_pool(const u16* __restrict__ h, const int* __restrict__ batch,
                                              float* __restrict__ emb, int* __restrict__ gcnt) {
    int f = threadIdx.x;
    int base = blockIdx.x * 64;
    float acc = 0.f; int cnt = 0;
    int curg = batch[base];
    for (int i = 0; i < 64; i++) {
        int node = base + i;
        int g = batch[node];
        if (g != curg) {
            atomicAdd(&emb[curg * 128 + f], acc);
            if (f == 0) atomicAdd(&gcnt[curg], cnt);
            acc = 0.f; cnt = 0; curg = g;
        }
        acc += b2f((u32)h[(size_t)node * 128 + f]);
        cnt++;
    }
    atomicAdd(&emb[curg * 128 + f], acc);
    if (f == 0) atomicAdd(&gcnt[curg], cnt);
}

// ---------------- final: embedding + logits (f32 out) ----------------
__global__ __launch_bounds__(256) void k_final(const float* __restrict__ emb, const int* __restrict__ gcnt,
                                               const float* __restrict__ lw, const float* __restrict__ lb,
                                               float* __restrict__ out) {
    int t = threadIdx.x;
    for (int i = t; i < Gg * Hh; i += 256) {
        int g = i >> 7;
        float c = fmaxf((float)gcnt[g], 1.f);
        out[Gg * Cc + i] = emb[i] / c;
    }
    if (t < Gg * Cc) {
        int g = t / Cc, c = t % Cc;
        float cn = fmaxf((float)gcnt[g], 1.f);
        float s = lb[c];
        for (int f = 0; f < Hh; f++)
            s += (emb[g * 128 + f] / cn) * lw[f * Cc + c];
        out[t] = s;
    }
}

extern "C" void kernel_launch(void* const* d_in, const int* in_sizes, int n_in,
                              void* d_out, int out_size, void* d_ws, size_t ws_size,
                              hipStream_t stream) {
    const float* x       = (const float*)d_in[0];
    const int*   ei      = (const int*)d_in[1];
    const int*   batch   = (const int*)d_in[2];
    const float* w1_root = (const float*)d_in[3];
    const float* w1_rel  = (const float*)d_in[4];
    const float* b1      = (const float*)d_in[5];
    const float* w2_root = (const float*)d_in[6];
    const float* w2_rel  = (const float*)d_in[7];
    const float* b2      = (const float*)d_in[8];
    const float* w3      = (const float*)d_in[9];
    const float* b3      = (const float*)d_in[10];
    const float* w4      = (const float*)d_in[11];
    const float* b4      = (const float*)d_in[12];
    const float* w5      = (const float*)d_in[13];
    const float* b5      = (const float*)d_in[14];
    const float* lw      = (const float*)d_in[15];
    const float* lb      = (const float*)d_in[16];
    const int* srcp = ei;
    const int* dstp = ei + Ee;
    float* out = (float*)d_out;

    char* w = (char*)d_ws;
    size_t off = 0;
    auto alloc = [&](size_t bytes) { size_t r = off; off += (bytes + 255) & ~(size_t)255; return r; };
    int*   counts  = (int*)(w + alloc(Nn * 4));              // doubles as scatter cursor
    int*   row_ptr = (int*)(w + alloc((Nn + 1) * 4));        // padded offsets
    int*   colidx  = (int*)(w + alloc((size_t)PCAP * 4));    // padded colidx
    float* dinv    = (float*)(w + alloc((Nn + 1) * 4));      // +1: dinv[Nn]=0 for pad edges
    float* emb     = (float*)(w + alloc(Gg * Hh * 4));
    int*   gcnt    = (int*)(w + alloc(Gg * 4));
    int*   bsum    = (int*)(w + alloc(NB * 4));
    int*   boff    = (int*)(w + alloc(256 * 4));
    u16*   pw      = (u16*)(w + alloc(7 * 16384 * 2));
    u16*   xb      = (u16*)(w + alloc((size_t)(Nn + 1) * Hh * 2));  // +1 zero row
    u16*   agg     = (u16*)(w + alloc((size_t)Nn * Hh * 2));
    u16*   hA      = (u16*)(w + alloc((size_t)(Nn + 1) * Hh * 2));  // +1 zero row
    (void)ws_size;

    u16* pw1r = pw + 0 * 16384;
    u16* pw1l = pw + 1 * 16384;
    u16* pw2r = pw + 2 * 16384;
    u16* pw2l = pw + 3 * 16384;
    u16* pw3  = pw + 4 * 16384;
    u16* pw4  = pw + 5 * 16384;
    u16* pw5  = pw + 6 * 16384;
    const u16* nil = (const u16*)nullptr;

    // CSR build (padded) + casts/packs
    hipLaunchKernelGGL(k_init, dim3(157), dim3(256), 0, stream, counts, emb, gcnt);
    hipLaunchKernelGGL(k_count, dim3((Ee + 255) / 256), dim3(256), 0, stream, dstp, counts);
    hipLaunchKernelGGL(k_scan1, dim3(NB), dim3(256), 0, stream, counts, bsum);
    hipLaunchKernelGGL(k_scan2, dim3(1), dim3(256), 0, stream, bsum, boff, row_ptr);
    hipLaunchKernelGGL(k_scan3, dim3(NB), dim3(256), 0, stream, counts, boff, row_ptr, counts, dinv);
    hipLaunchKernelGGL(k_prefill, dim3((PCAP / 4 + 255) / 256), dim3(256), 0, stream, colidx, xb, hA, dinv);
    hipLaunchKernelGGL(k_scatter, dim3((Ee + 255) / 256), dim3(256), 0, stream, srcp, dstp, counts, colidx);
    hipLaunchKernelGGL(k_cast, dim3(Nn * Hh / 1024), dim3(256), 0, stream, x, xb);
    hipLaunchKernelGGL(k_pack, dim3((7 * 16384 + 255) / 256), dim3(256), 0, stream,
                       w1_root, w1_rel, w2_root, w2_rel, w3, w4, w5, pw);

    // layer 1 (GraphConv): hA = relu(xb@w1_root + agg(xb)@w1_rel + b1)
    hipLaunchKernelGGL(k_agg_plain, dim3(Nn / 16), dim3(256), 0, stream, xb, agg, row_ptr, colidx);
    hipLaunchKernelGGL(k_gemm, dim3(Nn / 64), dim3(256), 0, stream, xb, pw1r, agg, pw1l, b1, hA, 1, 1);
    // layer 2 (GraphConv), GEMM in-place on hA
    hipLaunchKernelGGL(k_agg_plain, dim3(Nn / 16), dim3(256), 0, stream, hA, agg, row_ptr, colidx);
    hipLaunchKernelGGL(k_gemm, dim3(Nn / 64), dim3(256), 0, stream, hA, pw2r, agg, pw2l, b2, hA, 1, 1);
    // layers 3..5 (GCNConv)
    hipLaunchKernelGGL(k_agg_gcn, dim3(Nn / 16), dim3(256), 0, stream, hA, agg, row_ptr, colidx, dinv);
    hipLaunchKernelGGL(k_gemm, dim3(Nn / 64), dim3(256), 0, stream, agg, pw3, nil, nil, b3, hA, 0, 1);
    hipLaunchKernelGGL(k_agg_gcn, dim3(Nn / 16), dim3(256), 0, stream, hA, agg, row_ptr, colidx, dinv);
    hipLaunchKernelGGL(k_gemm, dim3(Nn / 64), dim3(256), 0, stream, agg, pw4, nil, nil, b4, hA, 0, 1);
    hipLaunchKernelGGL(k_agg_gcn, dim3(Nn / 16), dim3(256), 0, stream, hA, agg, row_ptr, colidx, dinv);
    hipLaunchKernelGGL(k_gemm, dim3(Nn / 64), dim3(256), 0, stream, agg, pw5, nil, nil, b5, hA, 0, 0);

    // pool + final linear
    hipLaunchKernelGGL(k_pool, dim3(Nn / 64), dim3(128), 0, stream, hA, batch, emb, gcnt);
    hipLaunchKernelGGL(k_final, dim3(1), dim3(256), 0, stream, emb, gcnt, lw, lb, out);
}

// Round 11
// 328.123 us; speedup vs baseline: 1.3443x; 1.1681x over previous
//
#include <hip/hip_runtime.h>

#define Nn 40000
#define Ee 600000
#define Hh 128
#define Gg 32
#define Cc 6
#define NB 157              // ceil(Nn/256) scan blocks
#define PCAP (Ee + 8 * Nn)  // padded colidx capacity (920000)
#define LSTR 136            // LDS tile row stride in u16 (128 + 8 pad)

typedef __bf16 bf16x8 __attribute__((ext_vector_type(8)));
typedef float floatx4 __attribute__((ext_vector_type(4)));
typedef unsigned short u16;
typedef unsigned int u32;

__device__ __forceinline__ float b2f(u32 u) {
    union { u32 i; float f; } v; v.i = u << 16; return v.f;
}
__device__ __forceinline__ float b2f_hi(u32 u) {
    union { u32 i; float f; } v; v.i = u & 0xffff0000u; return v.f;
}
__device__ __forceinline__ u16 f2b(float f) {
    union { float f; u32 i; } v; v.f = f;
    u32 r = v.i + 0x7fffu + ((v.i >> 16) & 1u);   // RNE
    return (u16)(r >> 16);
}
__device__ __forceinline__ u32 pack2(float a, float b) {
    return (u32)f2b(a) | ((u32)f2b(b) << 16);
}

// ---------------- init ----------------
__global__ __launch_bounds__(256) void k_init(int* counts, float* emb, int* gcnt) {
    int i = blockIdx.x * 256 + threadIdx.x;
    if (i < Nn) counts[i] = 0;
    if (i < Gg * Hh) emb[i] = 0.f;
    if (i < Gg) gcnt[i] = 0;
}

__global__ __launch_bounds__(256) void k_count(const int* __restrict__ dst, int* __restrict__ counts) {
    int i = blockIdx.x * 256 + threadIdx.x;
    if (i < Ee) atomicAdd(&counts[dst[i]], 1);
}

// ---------------- 3-phase multi-block exclusive scan over PADDED counts ----------------
__global__ __launch_bounds__(256) void k_scan1(const int* __restrict__ counts, int* __restrict__ bsum) {
    __shared__ int sm[256];
    int t = threadIdx.x;
    int i = blockIdx.x * 256 + t;
    sm[t] = (i < Nn) ? ((counts[i] + 7) & ~7) : 0;
    __syncthreads();
    for (int ofs = 128; ofs > 0; ofs >>= 1) {
        if (t < ofs) sm[t] += sm[t + ofs];
        __syncthreads();
    }
    if (t == 0) bsum[blockIdx.x] = sm[0];
}

__global__ __launch_bounds__(256) void k_scan2(const int* __restrict__ bsum, int* __restrict__ boff,
                                               int* __restrict__ row_ptr) {
    __shared__ int sm[256];
    int t = threadIdx.x;
    int v = (t < NB) ? bsum[t] : 0;
    sm[t] = v;
    __syncthreads();
    for (int ofs = 1; ofs < 256; ofs <<= 1) {
        int u = (t >= ofs) ? sm[t - ofs] : 0;
        __syncthreads();
        sm[t] += u;
        __syncthreads();
    }
    if (t < NB) boff[t] = sm[t] - v;
    if (t == 255) row_ptr[Nn] = sm[255];
}

// cursor may alias counts — each thread reads counts[i] before writing cursor[i].
__global__ __launch_bounds__(256) void k_scan3(const int* counts, const int* __restrict__ boff,
                                               int* row_ptr, int* cursor, float* dinv) {
    __shared__ int sm[256];
    int t = threadIdx.x;
    int i = blockIdx.x * 256 + t;
    int c = (i < Nn) ? counts[i] : 0;
    int pc = (c + 7) & ~7;
    sm[t] = pc;
    __syncthreads();
    for (int ofs = 1; ofs < 256; ofs <<= 1) {
        int u = (t >= ofs) ? sm[t - ofs] : 0;
        __syncthreads();
        sm[t] += u;
        __syncthreads();
    }
    if (i < Nn) {
        int excl = sm[t] - pc + boff[blockIdx.x];
        row_ptr[i] = excl;
        cursor[i] = excl;
        dinv[i] = rsqrtf((float)(c + 1));
    }
}

// ---------------- prefill padded colidx with dummy node Nn; zero dummy rows; dinv[Nn]=0 ----------------
__global__ __launch_bounds__(256) void k_prefill(int* __restrict__ pcol, u16* __restrict__ xb,
                                                 u16* __restrict__ hA, u16* __restrict__ hB,
                                                 float* __restrict__ dinv) {
    int i = blockIdx.x * 256 + threadIdx.x;
    if (i < PCAP / 4) {
        int4 v = { Nn, Nn, Nn, Nn };
        *(int4*)(pcol + i * 4) = v;
    }
    if (blockIdx.x == 0) {
        int t = threadIdx.x;
        uint4 z = { 0, 0, 0, 0 };
        if (t < 16)              *(uint4*)(xb + (size_t)Nn * 128 + t * 8) = z;
        else if (t < 32)         *(uint4*)(hA + (size_t)Nn * 128 + (t - 16) * 8) = z;
        else if (t < 48)         *(uint4*)(hB + (size_t)Nn * 128 + (t - 32) * 8) = z;
        else if (t == 48)        dinv[Nn] = 0.f;
    }
}

__global__ __launch_bounds__(256) void k_scatter(const int* __restrict__ src, const int* __restrict__ dst,
                                                 int* __restrict__ cursor, int* __restrict__ colidx) {
    int i = blockIdx.x * 256 + threadIdx.x;
    if (i < Ee) {
        int d = dst[i];
        int p = atomicAdd(&cursor[d], 1);
        if ((u32)p < (u32)PCAP) colidx[p] = src[i];
    }
}

// ---------------- f32 -> bf16 cast of input features (flat rows) ----------------
__global__ __launch_bounds__(256) void k_cast(const float* __restrict__ x, u16* __restrict__ xb) {
    int i = (blockIdx.x * 256 + threadIdx.x) * 4;
    float4 v = *(const float4*)(x + i);
    ushort4 o = { f2b(v.x), f2b(v.y), f2b(v.z), f2b(v.w) };
    *(ushort4*)(xb + i) = o;
}

// ---------------- weight packing: f32 [K=128][N=128] -> bf16 MFMA B-fragment order ----------------
__global__ __launch_bounds__(256) void k_pack(const float* w0, const float* w1, const float* w2,
                                              const float* w3, const float* w4, const float* w5,
                                              const float* w6, u16* dst) {
    int idx = blockIdx.x * 256 + threadIdx.x;
    if (idx >= 7 * 16384) return;
    const float* ws[7] = { w0, w1, w2, w3, w4, w5, w6 };
    int mat = idx >> 14, r = idx & 16383;
    int j = r & 7, n = (r >> 3) & 15, q = (r >> 7) & 3, nt = (r >> 9) & 7, t = r >> 12;
    dst[idx] = f2b(ws[mat][(t * 32 + q * 8 + j) * 128 + nt * 16 + n]);
}

// ---------------- FUSED layer: agg (gather) -> LDS -> 16-row MFMA GEMM ----------------
// GraphConv (gcn=0): hout = relu(hin@Broot + agg(hin)@Bagg + b)   (dual A)
// GCNConv   (gcn=1): hout = [relu]( [di*sum ds*hin_s + di^2*hin_i]@Bagg + b )
// Block = 16 nodes, 256 threads. Padded CSR (trip counts multiple of 8, pads hit zero row Nn).
#define UNPACK_ADD(V)                                   \
    a0 += b2f((V).x);  a1 += b2f_hi((V).x);             \
    a2 += b2f((V).y);  a3 += b2f_hi((V).y);             \
    a4 += b2f((V).z);  a5 += b2f_hi((V).z);             \
    a6 += b2f((V).w);  a7 += b2f_hi((V).w);

#define UNPACK_FMA(V, d)                                      \
    a0 += (d) * b2f((V).x);  a1 += (d) * b2f_hi((V).x);       \
    a2 += (d) * b2f((V).y);  a3 += (d) * b2f_hi((V).y);       \
    a4 += (d) * b2f((V).z);  a5 += (d) * b2f_hi((V).z);       \
    a6 += (d) * b2f((V).w);  a7 += (d) * b2f_hi((V).w);

__global__ __launch_bounds__(256) void k_layer(const u16* __restrict__ hin,
                                               const u16* __restrict__ Bp_agg,
                                               const u16* __restrict__ Bp_self,
                                               const float* __restrict__ bias,
                                               u16* __restrict__ hout,
                                               const int* __restrict__ prow,
                                               const int* __restrict__ pcol,
                                               const float* __restrict__ dinv,
                                               int gcn, int relu) {
    __shared__ u16 Asm[16 * LSTR];
    int wave = threadIdx.x >> 6, lane = threadIdx.x & 63;
    int m0 = blockIdx.x * 16;

    // ---- phase A: aggregate this block's 16 nodes (4 per wave, 16 lanes each) ----
    {
        int g = lane >> 4, l = lane & 15;
        int nloc = wave * 4 + g;
        int node = m0 + nloc;
        int beg = prow[node], end = prow[node + 1];
        float a0 = 0.f, a1 = 0.f, a2 = 0.f, a3 = 0.f, a4 = 0.f, a5 = 0.f, a6 = 0.f, a7 = 0.f;
        const u16* base = hin + l * 8;
        int4 i0 = {0,0,0,0}, i1 = {0,0,0,0};
        if (beg < end) {
            i0 = *(const int4*)(pcol + beg);
            i1 = *(const int4*)(pcol + beg + 4);
        }
        if (gcn) {
            for (int e = beg; e < end; e += 8) {
                int en = (e + 8 < end) ? (e + 8) : beg;
                int4 j0 = *(const int4*)(pcol + en);
                int4 j1 = *(const int4*)(pcol + en + 4);
                float d0 = dinv[i0.x], d1 = dinv[i0.y], d2 = dinv[i0.z], d3 = dinv[i0.w];
                float d4 = dinv[i1.x], d5 = dinv[i1.y], d6 = dinv[i1.z], d7 = dinv[i1.w];
                uint4 v0 = *(const uint4*)(base + (size_t)i0.x * 128);
                uint4 v1 = *(const uint4*)(base + (size_t)i0.y * 128);
                uint4 v2 = *(const uint4*)(base + (size_t)i0.z * 128);
                uint4 v3 = *(const uint4*)(base + (size_t)i0.w * 128);
                uint4 v4 = *(const uint4*)(base + (size_t)i1.x * 128);
                uint4 v5 = *(const uint4*)(base + (size_t)i1.y * 128);
                uint4 v6 = *(const uint4*)(base + (size_t)i1.z * 128);
                uint4 v7 = *(const uint4*)(base + (size_t)i1.w * 128);
                UNPACK_FMA(v0, d0) UNPACK_FMA(v1, d1) UNPACK_FMA(v2, d2) UNPACK_FMA(v3, d3)
                UNPACK_FMA(v4, d4) UNPACK_FMA(v5, d5) UNPACK_FMA(v6, d6) UNPACK_FMA(v7, d7)
                i0 = j0; i1 = j1;
            }
            float di = dinv[node];
            float d2n = di * di;
            uint4 us = *(const uint4*)(base + (size_t)node * 128);
            a0 = di * a0 + d2n * b2f(us.x);  a1 = di * a1 + d2n * b2f_hi(us.x);
            a2 = di * a2 + d2n * b2f(us.y);  a3 = di * a3 + d2n * b2f_hi(us.y);
            a4 = di * a4 + d2n * b2f(us.z);  a5 = di * a5 + d2n * b2f_hi(us.z);
            a6 = di * a6 + d2n * b2f(us.w);  a7 = di * a7 + d2n * b2f_hi(us.w);
        } else {
            for (int e = beg; e < end; e += 8) {
                int en = (e + 8 < end) ? (e + 8) : beg;
                int4 j0 = *(const int4*)(pcol + en);
                int4 j1 = *(const int4*)(pcol + en + 4);
                uint4 v0 = *(const uint4*)(base + (size_t)i0.x * 128);
                uint4 v1 = *(const uint4*)(base + (size_t)i0.y * 128);
                uint4 v2 = *(const uint4*)(base + (size_t)i0.z * 128);
                uint4 v3 = *(const uint4*)(base + (size_t)i0.w * 128);
                uint4 v4 = *(const uint4*)(base + (size_t)i1.x * 128);
                uint4 v5 = *(const uint4*)(base + (size_t)i1.y * 128);
                uint4 v6 = *(const uint4*)(base + (size_t)i1.z * 128);
                uint4 v7 = *(const uint4*)(base + (size_t)i1.w * 128);
                UNPACK_ADD(v0) UNPACK_ADD(v1) UNPACK_ADD(v2) UNPACK_ADD(v3)
                UNPACK_ADD(v4) UNPACK_ADD(v5) UNPACK_ADD(v6) UNPACK_ADD(v7)
                i0 = j0; i1 = j1;
            }
        }
        uint4 o = { pack2(a0, a1), pack2(a2, a3), pack2(a4, a5), pack2(a6, a7) };
        *(uint4*)&Asm[nloc * LSTR + l * 8] = o;
    }
    __syncthreads();

    // ---- phase B: 16-row GEMM; wave handles cols [wave*32, wave*32+32) ----
    {
        int n = lane & 15, q = lane >> 4;
        floatx4 acc0 = (floatx4){0.f, 0.f, 0.f, 0.f};
        floatx4 acc1 = (floatx4){0.f, 0.f, 0.f, 0.f};
        int nt0 = wave * 2, nt1 = wave * 2 + 1;
#pragma unroll
        for (int t = 0; t < 4; t++) {
            bf16x8 a = *(const bf16x8*)&Asm[n * LSTR + q * 8 + t * 32];
            const u16* bp = Bp_agg + t * 4096 + q * 128 + n * 8;
            bf16x8 b0 = *(const bf16x8*)(bp + nt0 * 512);
            bf16x8 b1 = *(const bf16x8*)(bp + nt1 * 512);
            acc0 = __builtin_amdgcn_mfma_f32_16x16x32_bf16(a, b0, acc0, 0, 0, 0);
            acc1 = __builtin_amdgcn_mfma_f32_16x16x32_bf16(a, b1, acc1, 0, 0, 0);
        }
        if (!gcn) {
            const u16* arow = hin + (size_t)(m0 + n) * 128 + q * 8;
#pragma unroll
            for (int t = 0; t < 4; t++) {
                bf16x8 a = *(const bf16x8*)(arow + t * 32);
                const u16* bp = Bp_self + t * 4096 + q * 128 + n * 8;
                bf16x8 b0 = *(const bf16x8*)(bp + nt0 * 512);
                bf16x8 b1 = *(const bf16x8*)(bp + nt1 * 512);
                acc0 = __builtin_amdgcn_mfma_f32_16x16x32_bf16(a, b0, acc0, 0, 0, 0);
                acc1 = __builtin_amdgcn_mfma_f32_16x16x32_bf16(a, b1, acc1, 0, 0, 0);
            }
        }
        // D: row = q*4 + r, col = nt*16 + n
#pragma unroll
        for (int j = 0; j < 2; j++) {
            int nt = wave * 2 + j;
            int col = nt * 16 + n;
            float bv = bias[col];
            floatx4 ac = j ? acc1 : acc0;
#pragma unroll
            for (int r = 0; r < 4; r++) {
                float v = ac[r] + bv;
                if (relu) v = fmaxf(v, 0.f);
                hout[(size_t)(m0 + q * 4 + r) * 128 + col] = f2b(v);
            }
        }
    }
}

// ---------------- mean-pool (batch is sorted), bf16 in, f32 accum ----------------
__global__ __launch_bounds__(128) void k_pool(const u16* __restrict__ h, const int* __restrict__ batch,
                                              float* __restrict__ emb, int* __restrict__ gcnt) {
    int f = threadIdx.x;
    int base = blockIdx.x * 64;
    float acc = 0.f; int cnt = 0;
    int curg = batch[base];
    for (int i = 0; i < 64; i++) {
        int node = base + i;
        int g = batch[node];
        if (g != curg) {
            atomicAdd(&emb[curg * 128 + f], acc);
            if (f == 0) atomicAdd(&gcnt[curg], cnt);
            acc = 0.f; cnt = 0; curg = g;
        }
        acc += b2f((u32)h[(size_t)node * 128 + f]);
        cnt++;
    }
    atomicAdd(&emb[curg * 128 + f], acc);
    if (f == 0) atomicAdd(&gcnt[curg], cnt);
}

// ---------------- final: embedding + logits (f32 out) ----------------
__global__ __launch_bounds__(256) void k_final(const float* __restrict__ emb, const int* __restrict__ gcnt,
                                               const float* __restrict__ lw, const float* __restrict__ lb,
                                               float* __restrict__ out) {
    int t = threadIdx.x;
    for (int i = t; i < Gg * Hh; i += 256) {
        int g = i >> 7;
        float c = fmaxf((float)gcnt[g], 1.f);
        out[Gg * Cc + i] = emb[i] / c;
    }
    if (t < Gg * Cc) {
        int g = t / Cc, c = t % Cc;
        float cn = fmaxf((float)gcnt[g], 1.f);
        float s = lb[c];
        for (int f = 0; f < Hh; f++)
            s += (emb[g * 128 + f] / cn) * lw[f * Cc + c];
        out[t] = s;
    }
}

extern "C" void kernel_launch(void* const* d_in, const int* in_sizes, int n_in,
                              void* d_out, int out_size, void* d_ws, size_t ws_size,
                              hipStream_t stream) {
    const float* x       = (const float*)d_in[0];
    const int*   ei      = (const int*)d_in[1];
    const int*   batch   = (const int*)d_in[2];
    const float* w1_root = (const float*)d_in[3];
    const float* w1_rel  = (const float*)d_in[4];
    const float* b1      = (const float*)d_in[5];
    const float* w2_root = (const float*)d_in[6];
    const float* w2_rel  = (const float*)d_in[7];
    const float* b2      = (const float*)d_in[8];
    const float* w3      = (const float*)d_in[9];
    const float* b3      = (const float*)d_in[10];
    const float* w4      = (const float*)d_in[11];
    const float* b4      = (const float*)d_in[12];
    const float* w5      = (const float*)d_in[13];
    const float* b5      = (const float*)d_in[14];
    const float* lw      = (const float*)d_in[15];
    const float* lb      = (const float*)d_in[16];
    const int* srcp = ei;
    const int* dstp = ei + Ee;
    float* out = (float*)d_out;

    char* w = (char*)d_ws;
    size_t off = 0;
    auto alloc = [&](size_t bytes) { size_t r = off; off += (bytes + 255) & ~(size_t)255; return r; };
    int*   counts  = (int*)(w + alloc(Nn * 4));              // doubles as scatter cursor
    int*   row_ptr = (int*)(w + alloc((Nn + 1) * 4));        // padded offsets
    int*   colidx  = (int*)(w + alloc((size_t)PCAP * 4));    // padded colidx
    float* dinv    = (float*)(w + alloc((Nn + 1) * 4));      // +1: dinv[Nn]=0 for pad edges
    float* emb     = (float*)(w + alloc(Gg * Hh * 4));
    int*   gcnt    = (int*)(w + alloc(Gg * 4));
    int*   bsum    = (int*)(w + alloc(NB * 4));
    int*   boff    = (int*)(w + alloc(256 * 4));
    u16*   pw      = (u16*)(w + alloc(7 * 16384 * 2));
    u16*   xb      = (u16*)(w + alloc((size_t)(Nn + 1) * Hh * 2));  // +1 zero row
    u16*   hA      = (u16*)(w + alloc((size_t)(Nn + 1) * Hh * 2));  // +1 zero row
    u16*   hB      = (u16*)(w + alloc((size_t)(Nn + 1) * Hh * 2));  // +1 zero row
    (void)ws_size;

    u16* pw1r = pw + 0 * 16384;
    u16* pw1l = pw + 1 * 16384;
    u16* pw2r = pw + 2 * 16384;
    u16* pw2l = pw + 3 * 16384;
    u16* pw3  = pw + 4 * 16384;
    u16* pw4  = pw + 5 * 16384;
    u16* pw5  = pw + 6 * 16384;
    const u16* nil = (const u16*)nullptr;

    // CSR build (padded) + casts/packs
    hipLaunchKernelGGL(k_init, dim3(157), dim3(256), 0, stream, counts, emb, gcnt);
    hipLaunchKernelGGL(k_count, dim3((Ee + 255) / 256), dim3(256), 0, stream, dstp, counts);
    hipLaunchKernelGGL(k_scan1, dim3(NB), dim3(256), 0, stream, counts, bsum);
    hipLaunchKernelGGL(k_scan2, dim3(1), dim3(256), 0, stream, bsum, boff, row_ptr);
    hipLaunchKernelGGL(k_scan3, dim3(NB), dim3(256), 0, stream, counts, boff, row_ptr, counts, dinv);
    hipLaunchKernelGGL(k_prefill, dim3((PCAP / 4 + 255) / 256), dim3(256), 0, stream, colidx, xb, hA, hB, dinv);
    hipLaunchKernelGGL(k_scatter, dim3((Ee + 255) / 256), dim3(256), 0, stream, srcp, dstp, counts, colidx);
    hipLaunchKernelGGL(k_cast, dim3(Nn * Hh / 1024), dim3(256), 0, stream, x, xb);
    hipLaunchKernelGGL(k_pack, dim3((7 * 16384 + 255) / 256), dim3(256), 0, stream,
                       w1_root, w1_rel, w2_root, w2_rel, w3, w4, w5, pw);

    // fused layers (block = 16 nodes, 2500 blocks)
    // L1 GraphConv: xb -> hA
    hipLaunchKernelGGL(k_layer, dim3(Nn / 16), dim3(256), 0, stream,
                       xb, pw1l, pw1r, b1, hA, row_ptr, colidx, dinv, 0, 1);
    // L2 GraphConv: hA -> hB
    hipLaunchKernelGGL(k_layer, dim3(Nn / 16), dim3(256), 0, stream,
                       hA, pw2l, pw2r, b2, hB, row_ptr, colidx, dinv, 0, 1);
    // L3 GCN: hB -> hA
    hipLaunchKernelGGL(k_layer, dim3(Nn / 16), dim3(256), 0, stream,
                       hB, pw3, nil, b3, hA, row_ptr, colidx, dinv, 1, 1);
    // L4 GCN: hA -> hB
    hipLaunchKernelGGL(k_layer, dim3(Nn / 16), dim3(256), 0, stream,
                       hA, pw4, nil, b4, hB, row_ptr, colidx, dinv, 1, 1);
    // L5 GCN (no relu): hB -> hA
    hipLaunchKernelGGL(k_layer, dim3(Nn / 16), dim3(256), 0, stream,
                       hB, pw5, nil, b5, hA, row_ptr, colidx, dinv, 1, 0);

    // pool + final linear
    hipLaunchKernelGGL(k_pool, dim3(Nn / 64), dim3(128), 0, stream, hA, batch, emb, gcnt);
    hipLaunchKernelGGL(k_final, dim3(1), dim3(256), 0, stream, emb, gcnt, lw, lb, out);
}